// Round 16
// baseline (96.436 us; speedup 1.0000x reference)
//
#include <hip/hip_runtime.h>
#include <hip/hip_bf16.h>

// CapsuleNet dynamic routing, fused per-sample. fp32 I/O:
// x: f32 [8192, 32, 8], W: f32 [32, 8, 256], out: f32 [8192, 16, 16].
// r16: S=4 samples/block (halves the 512 MB per-pass W L2 stream; W loads
// amortized over 4 samples). Samples packed as two v2h pairs (01, 23).
// Butterfly: cndmask selects + DPP transports (levels 8/2/1 xor-DPP, level 4
// masked dual-DPP). c f16 pairs, stride 41 v2h: softmax writes 2 lanes/bank
// (free), c.uh reads 4 distinct broadcast addrs (banks j/j+9/j+18/j+27).
// x reads: wave-uniform loads of pre-converted f16 (L1 broadcast).

#define S 4

typedef float    v2f __attribute__((ext_vector_type(2)));
typedef _Float16 v2h __attribute__((ext_vector_type(2)));

__device__ __forceinline__ v2h pack2h(float a, float b) {
  return __builtin_bit_cast(v2h, __builtin_amdgcn_cvt_pkrtz(a, b));  // v_cvt_pkrtz_f16_f32
}

// DPP cross-lane: value of `x` from lane (lane ^ k) within a 16-lane row.
// 0xB1 = quad_perm[1,0,3,2] (xor1)  0x4E = quad_perm[2,3,0,1] (xor2)
// 0x128 = row_ror:8 (xor8)  0x141 = row_half_mirror  0x140 = row_mirror
template <int CTRL>
__device__ __forceinline__ float dppf(float x) {
  return __builtin_bit_cast(float,
      __builtin_amdgcn_update_dpp(0, __builtin_bit_cast(int, x), CTRL, 0xF, 0xF, true));
}
template <int CTRL>
__device__ __forceinline__ v2h dpph(v2h v) {  // both samples in one DPP
  return __builtin_bit_cast(v2h,
      __builtin_amdgcn_update_dpp(0, __builtin_bit_cast(int, v), CTRL, 0xF, 0xF, true));
}
// Masked DPP keeping `old` on disabled banks (bound_ctrl=false: keep old).
template <int CTRL, int BANK>
__device__ __forceinline__ int dpp_old_i(int old, int x) {
  return __builtin_amdgcn_update_dpp(old, x, CTRL, 0xF, BANK, false);
}
// Deliver partner(lane^4)'s value of s to every lane (validated r10/r13):
// banks 0,2 (lanes 0-3,8-11): from lane+4 via row_shl:4 (0x104);
// banks 1,3 (lanes 4-7,12-15): from lane-4 via row_shr:4 (0x114).
__device__ __forceinline__ v2h xor4t_h(v2h s) {
  int si = __builtin_bit_cast(int, s);
  int ya = dpp_old_i<0x104, 0x5>(0, si);
  return __builtin_bit_cast(v2h, dpp_old_i<0x114, 0xA>(ya, si));
}

#if __has_builtin(__builtin_amdgcn_fdot2)
__device__ __forceinline__ float dot2(v2h a, v2h b, float c) {
  return __builtin_amdgcn_fdot2(a, b, c, false);  // v_dot2_f32_f16
}
#else
__device__ __forceinline__ float dot2(v2h a, v2h b, float c) {
  return fmaf((float)a.x, (float)b.x, fmaf((float)a.y, (float)b.y, c));
}
#endif

// Fused prep: blocks 0..255: W[ic][id][k](f32) -> Wth[ic][k][id](f16);
// blocks 256..1279: x (f32) -> xh (f16), 8 elems/thread.
__global__ __launch_bounds__(256) void prep_kernel(const float* __restrict__ W,
                                                   const float* __restrict__ x,
                                                   _Float16* __restrict__ Wth,
                                                   _Float16* __restrict__ xh) {
  int bid = blockIdx.x;
  if (bid < 256) {
    int o  = bid * 256 + threadIdx.x;
    int ic = o >> 11;
    int k  = (o >> 3) & 255;
    int id = o & 7;
    Wth[o] = (_Float16)W[(ic * 8 + id) * 256 + k];
  } else {
    int tid = (bid - 256) * 256 + threadIdx.x;
    const float4* xp = (const float4*)x + tid * 2;
    float4 f0 = xp[0], f1 = xp[1];
    v2h h0 = {(_Float16)f0.x, (_Float16)f0.y};
    v2h h1 = {(_Float16)f0.z, (_Float16)f0.w};
    v2h h2 = {(_Float16)f1.x, (_Float16)f1.y};
    v2h h3 = {(_Float16)f1.z, (_Float16)f1.w};
    uint4 o;
    o.x = __builtin_bit_cast(unsigned, h0);
    o.y = __builtin_bit_cast(unsigned, h1);
    o.z = __builtin_bit_cast(unsigned, h2);
    o.w = __builtin_bit_cast(unsigned, h3);
    ((uint4*)xh)[tid] = o;
  }
}

// squash over the 16 dc lanes, two samples at once; DPP-only reduction (f32).
__device__ __forceinline__ v2f squash2(v2f o) {
  v2f s2 = o * o;
  s2.x += dppf<0xB1>(s2.x);   s2.y += dppf<0xB1>(s2.y);    // + lane^1
  s2.x += dppf<0x4E>(s2.x);   s2.y += dppf<0x4E>(s2.y);    // + lane^2
  s2.x += dppf<0x141>(s2.x);  s2.y += dppf<0x141>(s2.y);   // + lane^7
  s2.x += dppf<0x140>(s2.x);  s2.y += dppf<0x140>(s2.y);   // + lane^15
  s2 += (v2f){1e-7f, 1e-7f};
  v2f sc;
  sc.x = s2.x * __builtin_amdgcn_rsqf(s2.x) * __builtin_amdgcn_rcpf(1.f + s2.x);
  sc.y = s2.y * __builtin_amdgcn_rsqf(s2.y) * __builtin_amdgcn_rcpf(1.f + s2.y);
  return o * sc;  // sqrt(s2)/(1+s2) * o
}

// Butterfly transpose-reduction for 4 samples (two packed pairs). Lane dc
// lands b[icb+dc] (f32) for all four samples.
template <bool ASSIGN>
__device__ __forceinline__ void b_update4(v2h vh01, v2h vh23,
                                          const v2h* uh01, const v2h* uh23, int dc,
                                          float* bp0, float* bp1,
                                          float* bp2, float* bp3) {
#pragma unroll
  for (int icb = 0; icb < 32; icb += 16) {
    v2h a01[16], a23[16];
#pragma unroll
    for (int j = 0; j < 16; ++j) {
      a01[j] = vh01 * uh01[icb + j];  // pk_mul_f16
      a23[j] = vh23 * uh23[icb + j];
    }
    v2h b801[8], b823[8];
    const bool u8 = (dc & 8) != 0;
#pragma unroll
    for (int j = 0; j < 8; ++j) {
      v2h s01 = u8 ? a01[j] : a01[j + 8];
      v2h s23 = u8 ? a23[j] : a23[j + 8];
      b801[j] = (u8 ? a01[j + 8] : a01[j]) + dpph<0x128>(s01);  // + lane^8
      b823[j] = (u8 ? a23[j + 8] : a23[j]) + dpph<0x128>(s23);
    }
    v2h c401[4], c423[4];
    const bool u4 = (dc & 4) != 0;
#pragma unroll
    for (int j = 0; j < 4; ++j) {
      v2h s01 = u4 ? b801[j] : b801[j + 4];
      v2h s23 = u4 ? b823[j] : b823[j + 4];
      c401[j] = (u4 ? b801[j + 4] : b801[j]) + xor4t_h(s01);    // + lane^4
      c423[j] = (u4 ? b823[j + 4] : b823[j]) + xor4t_h(s23);
    }
    v2h d201[2], d223[2];
    const bool u2 = (dc & 2) != 0;
#pragma unroll
    for (int j = 0; j < 2; ++j) {
      v2h s01 = u2 ? c401[j] : c401[j + 2];
      v2h s23 = u2 ? c423[j] : c423[j + 2];
      d201[j] = (u2 ? c401[j + 2] : c401[j]) + dpph<0x4E>(s01);  // + lane^2
      d223[j] = (u2 ? c423[j + 2] : c423[j]) + dpph<0x4E>(s23);
    }
    const bool u1 = (dc & 1) != 0;
    v2h s01 = u1 ? d201[0] : d201[1];
    v2h s23 = u1 ? d223[0] : d223[1];
    v2h e01 = (u1 ? d201[1] : d201[0]) + dpph<0xB1>(s01);        // + lane^1
    v2h e23 = (u1 ? d223[1] : d223[0]) + dpph<0xB1>(s23);
    if (ASSIGN) {
      bp0[icb + dc] = (float)e01.x;  bp1[icb + dc] = (float)e01.y;
      bp2[icb + dc] = (float)e23.x;  bp3[icb + dc] = (float)e23.y;
    } else {
      bp0[icb + dc] += (float)e01.x; bp1[icb + dc] += (float)e01.y;
      bp2[icb + dc] += (float)e23.x; bp3[icb + dc] += (float)e23.y;
    }
  }
}

#define CSTRIDE 41  // v2h per c-row: writes 2 lanes/bank; reads 4 distinct banks

__global__ __launch_bounds__(256, 4) void caps_kernel(const _Float16* __restrict__ xh,
                                                      const uint4* __restrict__ Wt4,
                                                      float* __restrict__ out) {
  const int t  = threadIdx.x;
  const int nc = t >> 4;
  const int dc = t & 15;
  const int s0 = blockIdx.x * S;

  __shared__ float b_lds[S][16][33];   // +1 pad: column reads 2 lanes/bank
  __shared__ v2h c01[16 * CSTRIDE];    // c[n][ic] samples 0,1
  __shared__ v2h c23[16 * CSTRIDE];    // c[n][ic] samples 2,3

  v2h uh01[32], uh23[32];              // packed (s,s+1), normal order
  v2f o01 = (v2f){0.f, 0.f}, o23 = (v2f){0.f, 0.f};

  // ---- u_hat: wave-uniform x loads (L1 broadcast) + one b128 W load/ic ----
  const v2h* xp0 = (const v2h*)(xh + (s0 + 0) * 256);
  const v2h* xp1 = (const v2h*)(xh + (s0 + 1) * 256);
  const v2h* xp2 = (const v2h*)(xh + (s0 + 2) * 256);
  const v2h* xp3 = (const v2h*)(xh + (s0 + 3) * 256);
#pragma unroll
  for (int ic = 0; ic < 32; ++ic) {
    uint4 wv = Wt4[ic * 256 + t];  // 8 f16 weights, one coalesced dwordx4
    v2h w0 = __builtin_bit_cast(v2h, wv.x);
    v2h w1 = __builtin_bit_cast(v2h, wv.y);
    v2h w2 = __builtin_bit_cast(v2h, wv.z);
    v2h w3 = __builtin_bit_cast(v2h, wv.w);
    float a0 = dot2(xp0[ic * 4 + 3], w3, dot2(xp0[ic * 4 + 2], w2,
               dot2(xp0[ic * 4 + 1], w1, dot2(xp0[ic * 4 + 0], w0, 0.f))));
    float a1 = dot2(xp1[ic * 4 + 3], w3, dot2(xp1[ic * 4 + 2], w2,
               dot2(xp1[ic * 4 + 1], w1, dot2(xp1[ic * 4 + 0], w0, 0.f))));
    float a2 = dot2(xp2[ic * 4 + 3], w3, dot2(xp2[ic * 4 + 2], w2,
               dot2(xp2[ic * 4 + 1], w1, dot2(xp2[ic * 4 + 0], w0, 0.f))));
    float a3 = dot2(xp3[ic * 4 + 3], w3, dot2(xp3[ic * 4 + 2], w2,
               dot2(xp3[ic * 4 + 1], w1, dot2(xp3[ic * 4 + 0], w0, 0.f))));
    o01 += (v2f){a0, a1};
    o23 += (v2f){a2, a3};
    uh01[ic] = pack2h(a0, a1);
    uh23[ic] = pack2h(a2, a3);
  }

  // ---- routing round 0: b = 0 => c = 1/16 ----
  {
    v2f v01 = squash2(o01 * (v2f){0.0625f, 0.0625f});
    v2f v23 = squash2(o23 * (v2f){0.0625f, 0.0625f});
    b_update4<true>(pack2h(v01.x, v01.y), pack2h(v23.x, v23.y), uh01, uh23, dc,
                    &b_lds[0][nc][0], &b_lds[1][nc][0],
                    &b_lds[2][nc][0], &b_lds[3][nc][0]);
  }
  __syncthreads();

  // ---- rounds 1, 2 ----
#pragma unroll
  for (int r = 1; r < 3; ++r) {
    {  // distributed softmax: thread -> (ss = t>>6, icc = (t>>1)&31, h = t&1)
      const int ss  = t >> 6;         // sample (wave-uniform)
      const int icc = (t >> 1) & 31;  // column
      const int h   = t & 1;          // rows 8h..8h+7
      float e[8];
      float sum = 0.f;
#pragma unroll
      for (int n = 0; n < 8; ++n) {
        e[n] = __expf(b_lds[ss][8 * h + n][icc]);  // no max-sub: |b| small
        sum += e[n];
      }
      sum += dppf<0xB1>(sum);  // lane^1 partner has same (ss,icc), other h
      float inv = __builtin_amdgcn_rcpf(sum);
      _Float16* cw = (_Float16*)(ss < 2 ? c01 : c23) + (ss & 1);
#pragma unroll
      for (int n = 0; n < 8; ++n)
        cw[((8 * h + n) * CSTRIDE + icc) * 2] = (_Float16)(e[n] * inv);
    }
    __syncthreads();

    // c.uh: compile-time offsets; 4 broadcast addrs/wave at distinct banks.
    const v2h* crow01 = &c01[nc * CSTRIDE];
    const v2h* crow23 = &c23[nc * CSTRIDE];
    v2h oh01 = (v2h){(_Float16)0.f, (_Float16)0.f};
    v2h oh23 = (v2h){(_Float16)0.f, (_Float16)0.f};
#pragma unroll
    for (int j = 0; j < 16; ++j) {
      oh01 = __builtin_elementwise_fma(crow01[j],      uh01[j],      oh01);
      oh01 = __builtin_elementwise_fma(crow01[j + 16], uh01[16 + j], oh01);
      oh23 = __builtin_elementwise_fma(crow23[j],      uh23[j],      oh23);
      oh23 = __builtin_elementwise_fma(crow23[j + 16], uh23[16 + j], oh23);
    }
    v2f v01 = squash2((v2f){(float)oh01.x, (float)oh01.y});
    v2f v23 = squash2((v2f){(float)oh23.x, (float)oh23.y});
    if (r == 2) {
      out[(s0 + 0) * 256 + t] = v01.x;
      out[(s0 + 1) * 256 + t] = v01.y;
      out[(s0 + 2) * 256 + t] = v23.x;
      out[(s0 + 3) * 256 + t] = v23.y;
    } else {
      b_update4<false>(pack2h(v01.x, v01.y), pack2h(v23.x, v23.y), uh01, uh23, dc,
                       &b_lds[0][nc][0], &b_lds[1][nc][0],
                       &b_lds[2][nc][0], &b_lds[3][nc][0]);
      __syncthreads();  // b complete before round-2 softmax; c overwrite safe
    }
  }
}

extern "C" void kernel_launch(void* const* d_in, const int* in_sizes, int n_in,
                              void* d_out, int out_size, void* d_ws, size_t ws_size,
                              hipStream_t stream) {
  const float* x = (const float*)d_in[0];
  const float* W = (const float*)d_in[1];
  _Float16* Wth = (_Float16*)d_ws;           // 128 KB: f16 W-transpose
  _Float16* xh  = (_Float16*)d_ws + 65536;   // 4 MB: f16 x

  prep_kernel<<<1280, 256, 0, stream>>>(W, x, Wth, xh);
  caps_kernel<<<8192 / S, 256, 0, stream>>>(xh, (const uint4*)Wth, (float*)d_out);
}